// Round 2
// baseline (1493.125 us; speedup 1.0000x reference)
//
#include <hip/hip_runtime.h>
#include <stdint.h>
#include <stddef.h>

// HiPPO-LegS scan as chunked causal convolution, fp16 MFMA, fp32 accumulate.
// Out[t] = sum_{j<=t} K[j] * x[t-j],  K[j] = dA^j dB  (since c_0 = 0).
// Chunk T=64:  t = 64k + r:
//   Out[t] = dA^{r+1} C_k + sum_{j=0}^{r} K[j] x[t-j],   C_k = Out[64k-1], C_0 = 0.
// C_k computed by pass1 directly from the long convolution -> no sequential phase.
//
// PRECISION (R1): all setup products (power doubling, K expansion) in
// double-fp16: X = X_hi + X_lo; A*B ~= Ah*Bh + Ah*Bl + Al*Bh, fp32 acc.
// Rationale: fp16(dA) perturbs slow-mode decay rates by ~0.5*dt -> e^{+-0.5}
// kernel error at j~2048 (observed 3.8e-3). Split chain keeps generator at
// ~2^-22; final hi-only roundings of K/x/C are incoherent (~1e-4 total).

typedef _Float16 f16;
typedef f16 half8 __attribute__((ext_vector_type(8)));
typedef float f32x4 __attribute__((ext_vector_type(4)));

#define SEQL 2048
#define NB 128
#define NS 256
#define PADROWS 64
#define LDA 72   // 64 + 8 halves: keeps ds_read_b128 16B-aligned, 2-way-max read conflicts
#define LDB 72

__device__ __forceinline__ half8 h8zero() {
  half8 v;
#pragma unroll
  for (int u = 0; u < 8; u++) v[u] = (f16)0.f;
  return v;
}

// --- staging helpers (blockDim.x == 512) ---

// dst[row][0..63] = src[row*sstride + 0..63]; rows >= nvalid -> 0
__device__ __forceinline__ void stage_rows(f16* dst, int ld, int nrows,
                                           const f16* src, int sstride,
                                           int nvalid, int tid) {
  int tasks = nrows * 8;
  for (int i = tid; i < tasks; i += 512) {
    int row = i >> 3, c = (i & 7) << 3;
    half8 v = h8zero();
    if (row < nvalid) v = *(const half8*)(src + (size_t)row * sstride + c);
    *(half8*)(dst + row * ld + c) = v;
  }
}

// As[b][q] = xpad[PADROWS + s_top - q][b]  (q=0..63, b=0..127), 0 if s < s_min
__device__ __forceinline__ void stage_revtrans(f16* As, const f16* xpad,
                                               int s_top, int s_min, int tid) {
  for (int i = tid; i < 1024; i += 512) {
    int q = i >> 4, bb = (i & 15) << 3;
    int s = s_top - q;
    half8 v = h8zero();
    if (s >= s_min) v = *(const half8*)(xpad + (size_t)(PADROWS + s) * NB + bb);
#pragma unroll
    for (int u = 0; u < 8; u++) As[(bb + u) * LDA + q] = v[u];
  }
}

// Bs[j][c] = X[(c0+c)*256 + j]  (j=0..255, c=0..63)  -- transposed stage
__device__ __forceinline__ void stage_trans(f16* Bs, const f16* X, int c0, int tid) {
  for (int i = tid; i < 2048; i += 512) {
    int c = i >> 5, jj = (i & 31) << 3;
    half8 v = *(const half8*)(X + (size_t)(c0 + c) * NS + jj);
#pragma unroll
    for (int u = 0; u < 8; u++) Bs[(jj + u) * LDB + c] = v[u];
  }
}

// --- MFMA core: one BK=64 chunk, block tile 128x256, 8 waves as 2(m) x 4(n) ---
__device__ __forceinline__ void mm64(const f16* As, const f16* Bs,
                                     f32x4 acc[4][4], int wm, int wn,
                                     int l15, int quad) {
#pragma unroll
  for (int ks = 0; ks < 64; ks += 32) {
    half8 a[4], b[4];
#pragma unroll
    for (int ms = 0; ms < 4; ms++)
      a[ms] = *(const half8*)(As + (wm * 64 + ms * 16 + l15) * LDA + ks + quad * 8);
#pragma unroll
    for (int ns = 0; ns < 4; ns++)
      b[ns] = *(const half8*)(Bs + (wn * 64 + ns * 16 + l15) * LDB + ks + quad * 8);
#pragma unroll
    for (int ms = 0; ms < 4; ms++)
#pragma unroll
      for (int ns = 0; ns < 4; ns++)
        acc[ms][ns] = __builtin_amdgcn_mfma_f32_16x16x32_f16(a[ms], b[ns], acc[ms][ns], 0, 0, 0);
  }
}

#define GEMM_PROLOGUE                                      \
  __shared__ alignas(16) f16 As[128 * LDA];                \
  __shared__ alignas(16) f16 Bs[256 * LDB];                \
  int tid = threadIdx.x;                                   \
  int lane = tid & 63, wid = tid >> 6;                     \
  int wm = wid >> 2, wn = wid & 3;                         \
  int l15 = lane & 15, quad = lane >> 4;                   \
  f32x4 acc[4][4];                                         \
  _Pragma("unroll") for (int ms = 0; ms < 4; ms++)         \
  _Pragma("unroll") for (int ns = 0; ns < 4; ns++)         \
  _Pragma("unroll") for (int u = 0; u < 4; u++) acc[ms][ns][u] = 0.f;

// --- prep: xpad fp16 [s][b], Cm[0]=0, PrH/PrL[0] = hi/lo(dA) ---
__global__ void k_prep(const float* __restrict__ x, const float* __restrict__ dA,
                       f16* __restrict__ xpad, f16* __restrict__ Cm,
                       f16* __restrict__ PrH0, f16* __restrict__ PrL0) {
  int gid = blockIdx.x * 256 + threadIdx.x;
  const int XPN = (PADROWS + SEQL) * NB;  // 270336
  if (gid < XPN) {
    int s = gid / NB - PADROWS;
    xpad[gid] = (s < 0) ? (f16)0.f : (f16)x[gid - PADROWS * NB];
  } else if (gid < XPN + NB * NS) {
    Cm[gid - XPN] = (f16)0.f;
  } else {
    int i = gid - (XPN + NB * NS);
    if (i < NS * NS) {
      float v = dA[i];
      f16 h = (f16)v;
      PrH0[i] = h;
      PrL0[i] = (f16)(v - (float)h);
    }
  }
}

// --- powers doubling round: dA^{m+r} = dA^m * dA^r, r = 1..m (split product) ---
__global__ void k_pow(f16* __restrict__ PrH, f16* __restrict__ PrL, int m) {
  int bi = blockIdx.x;
  int prod = bi >> 1, mtile = bi & 1;
  int r = prod + 1;
  const f16* AH = PrH + (size_t)(m - 1) * 65536;
  const f16* AL = PrL + (size_t)(m - 1) * 65536;
  const f16* BH = PrH + (size_t)(r - 1) * 65536;
  const f16* BL = PrL + (size_t)(r - 1) * 65536;
  f16* DH = PrH + (size_t)(m + r - 1) * 65536;
  f16* DL = PrL + (size_t)(m + r - 1) * 65536;
  GEMM_PROLOGUE
#pragma unroll 1
  for (int pass = 0; pass < 3; pass++) {
    const f16* Asrc = (pass == 2) ? AL : AH;
    const f16* Bsrc = (pass == 1) ? BL : BH;
#pragma unroll 1
    for (int cc = 0; cc < 4; cc++) {
      stage_rows(As, LDA, 128, Asrc + (size_t)(mtile * 128) * NS + cc * 64, NS, 128, tid);
      stage_trans(Bs, Bsrc, cc * 64, tid);
      __syncthreads();
      mm64(As, Bs, acc, wm, wn, l15, quad);
      __syncthreads();
    }
  }
#pragma unroll
  for (int ms = 0; ms < 4; ms++)
#pragma unroll
    for (int ns = 0; ns < 4; ns++)
#pragma unroll
      for (int u = 0; u < 4; u++) {
        int row = mtile * 128 + wm * 64 + ms * 16 + quad * 4 + u;
        int col = wn * 64 + ns * 16 + l15;
        float v = acc[ms][ns][u];
        f16 h = (f16)v;
        DH[(size_t)row * NS + col] = h;
        DL[(size_t)row * NS + col] = (f16)(v - (float)h);
      }
}

// --- K init: K[j] = dA^j dB, j=0..63 (fp32 dot with hi+lo power) ---
__global__ void k_kinit(const f16* __restrict__ PrH, const f16* __restrict__ PrL,
                        const float* __restrict__ dB,
                        f16* __restrict__ KjmH, f16* __restrict__ KjmL,
                        f16* __restrict__ KtH) {
  __shared__ float dBs[NS];
  int n = threadIdx.x, j = blockIdx.x;
  dBs[n] = dB[n];
  __syncthreads();
  float acc;
  if (j == 0) {
    acc = dBs[n];
  } else {
    const f16* rh = PrH + (size_t)(j - 1) * 65536 + (size_t)n * NS;
    const f16* rl = PrL + (size_t)(j - 1) * 65536 + (size_t)n * NS;
    acc = 0.f;
#pragma unroll 4
    for (int c = 0; c < NS; c += 8) {
      half8 vh = *(const half8*)(rh + c);
      half8 vl = *(const half8*)(rl + c);
#pragma unroll
      for (int u = 0; u < 8; u++) acc += ((float)vh[u] + (float)vl[u]) * dBs[c + u];
    }
  }
  f16 h = (f16)acc;
  f16 l = (f16)(acc - (float)h);
  KjmH[(size_t)j * NS + n] = h;
  KjmL[(size_t)j * NS + n] = l;
  KtH[(size_t)n * SEQL + j] = h;
}

// --- K expansion round: K[m+r] = dA^m K[r]; optionally dA^{2m} = sqsrc^2 (split) ---
__global__ void k_kexp(f16* __restrict__ KjmH, f16* __restrict__ KjmL,
                       f16* __restrict__ KtH,
                       const f16* __restrict__ AmH, const f16* __restrict__ AmL,
                       int jbase, int cols,
                       f16* __restrict__ sqdH, f16* __restrict__ sqdL,
                       const f16* __restrict__ sqsH, const f16* __restrict__ sqsL) {
  int bi = blockIdx.x;
  int nsq = (sqdH != nullptr) ? 2 : 0;
  GEMM_PROLOGUE
  if (bi < nsq) {  // squaring tile
    int mtile = bi;
#pragma unroll 1
    for (int pass = 0; pass < 3; pass++) {
      const f16* Asrc = (pass == 2) ? sqsL : sqsH;
      const f16* Bsrc = (pass == 1) ? sqsL : sqsH;
#pragma unroll 1
      for (int cc = 0; cc < 4; cc++) {
        stage_rows(As, LDA, 128, Asrc + (size_t)(mtile * 128) * NS + cc * 64, NS, 128, tid);
        stage_trans(Bs, Bsrc, cc * 64, tid);
        __syncthreads();
        mm64(As, Bs, acc, wm, wn, l15, quad);
        __syncthreads();
      }
    }
#pragma unroll
    for (int ms = 0; ms < 4; ms++)
#pragma unroll
      for (int ns = 0; ns < 4; ns++)
#pragma unroll
        for (int u = 0; u < 4; u++) {
          int row = mtile * 128 + wm * 64 + ms * 16 + quad * 4 + u;
          int col = wn * 64 + ns * 16 + l15;
          float v = acc[ms][ns][u];
          f16 h = (f16)v;
          sqdH[(size_t)row * NS + col] = h;
          sqdL[(size_t)row * NS + col] = (f16)(v - (float)h);
        }
    return;
  }
  bi -= nsq;
  int coltile = bi >> 1, mtile = bi & 1;
  int nvalid = cols - coltile * 256;
  if (nvalid > 256) nvalid = 256;
#pragma unroll 1
  for (int pass = 0; pass < 3; pass++) {
    const f16* Asrc = (pass == 2) ? AmL : AmH;
    const f16* Bsrc = (pass == 1) ? KjmL : KjmH;
#pragma unroll 1
    for (int cc = 0; cc < 4; cc++) {
      stage_rows(As, LDA, 128, Asrc + (size_t)(mtile * 128) * NS + cc * 64, NS, 128, tid);
      stage_rows(Bs, LDB, 256, Bsrc + (size_t)(coltile * 256) * NS + cc * 64, NS, nvalid, tid);
      __syncthreads();
      mm64(As, Bs, acc, wm, wn, l15, quad);
      __syncthreads();
    }
  }
#pragma unroll
  for (int ms = 0; ms < 4; ms++)
#pragma unroll
    for (int ns = 0; ns < 4; ns++)
#pragma unroll
      for (int u = 0; u < 4; u++) {
        int n = mtile * 128 + wm * 64 + ms * 16 + quad * 4 + u;
        int rr = coltile * 256 + wn * 64 + ns * 16 + l15;
        if (rr < cols) {
          int j = jbase + rr;
          float v = acc[ms][ns][u];
          f16 h = (f16)v;
          KjmH[(size_t)j * NS + n] = h;
          KjmL[(size_t)j * NS + n] = (f16)(v - (float)h);
          KtH[(size_t)n * SEQL + j] = h;
        }
      }
}

// --- pass1: boundary states C_{k+1} = Out[64k+63] via direct convolution ---
__global__ void k_pass1(const f16* __restrict__ Kt, const f16* __restrict__ xpad,
                        f16* __restrict__ Cm) {
  int k = blockIdx.x;  // 0..30
  int t = 64 * k + 63;
  GEMM_PROLOGUE
#pragma unroll 1
  for (int c = 0; c <= k; c++) {
    stage_revtrans(As, xpad, t - 64 * c, 0, tid);
    stage_rows(Bs, LDB, 256, Kt + 64 * c, SEQL, 256, tid);
    __syncthreads();
    mm64(As, Bs, acc, wm, wn, l15, quad);
    __syncthreads();
  }
  f16* C = Cm + (size_t)(k + 1) * (NB * NS);
#pragma unroll
  for (int ms = 0; ms < 4; ms++)
#pragma unroll
    for (int ns = 0; ns < 4; ns++)
#pragma unroll
      for (int u = 0; u < 4; u++) {
        int b = wm * 64 + ms * 16 + quad * 4 + u;
        int n = wn * 64 + ns * 16 + l15;
        C[(size_t)b * NS + n] = (f16)acc[ms][ns][u];
      }
}

// --- pass2: Out[64k+r] = dA^{r+1} C_k + sum_{j<=r} K[j] x[t-j] ---
__global__ void k_pass2(const f16* __restrict__ PrH, const f16* __restrict__ Kt,
                        const f16* __restrict__ xpad, const f16* __restrict__ Cm,
                        float* __restrict__ out) {
  int bi = blockIdx.x;
  int r = bi >> 5, k = bi & 31;  // 32 consecutive blocks share dA^{r+1} (L2 locality)
  int t = 64 * k + r;
  const f16* G = PrH + (size_t)r * 65536;  // dA^{r+1}
  GEMM_PROLOGUE
#pragma unroll 1
  for (int cc = 0; cc < 4; cc++) {  // C-part, inner dim m = 256
    stage_rows(As, LDA, 128, Cm + (size_t)k * (NB * NS) + cc * 64, NS, 128, tid);
    stage_rows(Bs, LDB, 256, G + cc * 64, NS, 256, tid);
    __syncthreads();
    mm64(As, Bs, acc, wm, wn, l15, quad);
    __syncthreads();
  }
  // window part, inner dim j = 64; mask j > r  <=>  s = t - j < 64k
  stage_revtrans(As, xpad, t, 64 * k, tid);
  stage_rows(Bs, LDB, 256, Kt, SEQL, 256, tid);
  __syncthreads();
  mm64(As, Bs, acc, wm, wn, l15, quad);
  __syncthreads();
  float* O = out + (size_t)t * (NB * NS);
#pragma unroll
  for (int ms = 0; ms < 4; ms++)
#pragma unroll
    for (int ns = 0; ns < 4; ns++)
#pragma unroll
      for (int u = 0; u < 4; u++) {
        int b = wm * 64 + ms * 16 + quad * 4 + u;
        int n = wn * 64 + ns * 16 + l15;
        O[(size_t)b * NS + n] = acc[ms][ns][u];
      }
}

extern "C" void kernel_launch(void* const* d_in, const int* in_sizes, int n_in,
                              void* d_out, int out_size, void* d_ws, size_t ws_size,
                              hipStream_t stream) {
  const float* x = (const float*)d_in[0];   // (2048, 128)
  const float* dA = (const float*)d_in[1];  // (256, 256)
  const float* dB = (const float*)d_in[2];  // (256,)
  float* out = (float*)d_out;

  char* ws = (char*)d_ws;
  f16* PrH = (f16*)(ws + 0);          // 64 * 65536 f16 (dA^1..dA^64) hi
  f16* PrL = (f16*)(ws + 8388608);    // lo
  f16* PBH = (f16*)(ws + 16777216);   // 4 * 65536 f16 (dA^{128,256,512,1024}) hi
  f16* PBL = (f16*)(ws + 17301504);   // lo
  f16* KjH = (f16*)(ws + 17825792);   // [j][n] 2048*256 hi
  f16* KjL = (f16*)(ws + 18874368);   // lo
  f16* KtH = (f16*)(ws + 19922944);   // [n][j] 256*2048 hi
  f16* Xp  = (f16*)(ws + 20971520);   // [2112][128]
  f16* Cm  = (f16*)(ws + 21512192);   // [32][128][256]
  // total ws use: 23,609,344 B (~22.5 MB)

  k_prep<<<1440, 256, 0, stream>>>(x, dA, Xp, Cm, PrH, PrL);
  for (int m = 1; m <= 32; m <<= 1)
    k_pow<<<2 * m, 512, 0, stream>>>(PrH, PrL, m);
  k_kinit<<<64, 256, 0, stream>>>(PrH, PrL, dB, KjH, KjL, KtH);
  // K expansion + fused squarings
  k_kexp<<<4, 512, 0, stream>>>(KjH, KjL, KtH, PrH + (size_t)63 * 65536, PrL + (size_t)63 * 65536,
                                64, 64, PBH + 0 * 65536, PBL + 0 * 65536,
                                PrH + (size_t)63 * 65536, PrL + (size_t)63 * 65536);
  k_kexp<<<4, 512, 0, stream>>>(KjH, KjL, KtH, PBH + 0 * 65536, PBL + 0 * 65536,
                                128, 128, PBH + 1 * 65536, PBL + 1 * 65536,
                                PBH + 0 * 65536, PBL + 0 * 65536);
  k_kexp<<<4, 512, 0, stream>>>(KjH, KjL, KtH, PBH + 1 * 65536, PBL + 1 * 65536,
                                256, 256, PBH + 2 * 65536, PBL + 2 * 65536,
                                PBH + 1 * 65536, PBL + 1 * 65536);
  k_kexp<<<6, 512, 0, stream>>>(KjH, KjL, KtH, PBH + 2 * 65536, PBL + 2 * 65536,
                                512, 512, PBH + 3 * 65536, PBL + 3 * 65536,
                                PBH + 2 * 65536, PBL + 2 * 65536);
  k_kexp<<<8, 512, 0, stream>>>(KjH, KjL, KtH, PBH + 3 * 65536, PBL + 3 * 65536,
                                1024, 1024, nullptr, nullptr, nullptr, nullptr);
  k_pass1<<<31, 512, 0, stream>>>(KtH, Xp, Cm);
  k_pass2<<<2048, 512, 0, stream>>>(PrH, KtH, Xp, Cm, out);
}

// Round 3
// 1490.112 us; speedup vs baseline: 1.0020x; 1.0020x over previous
//
#include <hip/hip_runtime.h>
#include <hip/hip_cooperative_groups.h>
#include <stdint.h>
#include <stddef.h>

namespace cg = cooperative_groups;

// HiPPO-LegS scan as chunked causal convolution, fp16 MFMA, fp32 accumulate.
// Out[64k+r] = dA^{r+1} C_k + sum_{j=0}^{r} K[j] x[t-j]
// C_{k+1} = sum_{i<=k} (dA^64)^{k-i} U_i  via Kogge-Stone scan over chunk sums
// U_k = sum_{j<64} K[j] x[64k+63-j].
// R3: whole setup (prep, 6 power rounds, K-init, U, 5 scan rounds) in ONE
// cooperative kernel with grid.sync between phases (was 14 tiny launches).
// Precision: dA powers + scan matrices S^d kept in split hi/lo fp16 (R2
// lesson: fp16(dA) alone perturbs slow-mode decay ~0.5*dt -> 4e-3 error).
// V (chunk-state scan values) kept fp32; K/x hi-only (incoherent roundings).

typedef _Float16 f16;
typedef f16 half8 __attribute__((ext_vector_type(8)));
typedef float f32x4 __attribute__((ext_vector_type(4)));

#define SEQL 2048
#define NB 128
#define NS 256
#define PADROWS 64
#define LDA 72   // 64+8 halves: 16B-aligned rows, only 2-way LDS read aliasing (free)
#define LDB 72

__device__ __forceinline__ half8 h8zero() {
  half8 v;
#pragma unroll
  for (int u = 0; u < 8; u++) v[u] = (f16)0.f;
  return v;
}

// --- staging helpers (blockDim.x == 512) ---

// dst[row][0..63] = src[row*sstride + 0..63] (f16 src); rows >= nvalid -> 0
__device__ __forceinline__ void stage_rows(f16* dst, int ld, int nrows,
                                           const f16* src, int sstride,
                                           int nvalid, int tid) {
  int tasks = nrows * 8;
  for (int i = tid; i < tasks; i += 512) {
    int row = i >> 3, c = (i & 7) << 3;
    half8 v = h8zero();
    if (row < nvalid) v = *(const half8*)(src + (size_t)row * sstride + c);
    *(half8*)(dst + row * ld + c) = v;
  }
}

// dst[row][0..63] = fp16(src_fp32[row*sstride + 0..63])
__device__ __forceinline__ void stage_rows32(f16* dst, int ld, int nrows,
                                             const float* src, int sstride, int tid) {
  int tasks = nrows * 8;
  for (int i = tid; i < tasks; i += 512) {
    int row = i >> 3, c = (i & 7) << 3;
    const float* p = src + (size_t)row * sstride + c;
    half8 v;
#pragma unroll
    for (int u = 0; u < 8; u++) v[u] = (f16)p[u];
    *(half8*)(dst + row * ld + c) = v;
  }
}

// As[b][q] = xpad[PADROWS + s_top - q][b]  (q=0..63, b=0..127), 0 if s < s_min
__device__ __forceinline__ void stage_revtrans(f16* As, const f16* xpad,
                                               int s_top, int s_min, int tid) {
  for (int i = tid; i < 1024; i += 512) {
    int q = i >> 4, bb = (i & 15) << 3;
    int s = s_top - q;
    half8 v = h8zero();
    if (s >= s_min) v = *(const half8*)(xpad + (size_t)(PADROWS + s) * NB + bb);
#pragma unroll
    for (int u = 0; u < 8; u++) As[(bb + u) * LDA + q] = v[u];
  }
}

// Bs[j][c] = X[(c0+c)*256 + j]  (j=0..255, c=0..63)  -- transposed stage
__device__ __forceinline__ void stage_trans(f16* Bs, const f16* X, int c0, int tid) {
  for (int i = tid; i < 2048; i += 512) {
    int c = i >> 5, jj = (i & 31) << 3;
    half8 v = *(const half8*)(X + (size_t)(c0 + c) * NS + jj);
#pragma unroll
    for (int u = 0; u < 8; u++) Bs[(jj + u) * LDB + c] = v[u];
  }
}

// --- MFMA core: one BK=64 chunk, block tile 128x256, 8 waves as 2(m) x 4(n) ---
__device__ __forceinline__ void mm64(const f16* As, const f16* Bs,
                                     f32x4 acc[4][4], int wm, int wn,
                                     int l15, int quad) {
#pragma unroll
  for (int ks = 0; ks < 64; ks += 32) {
    half8 a[4], b[4];
#pragma unroll
    for (int ms = 0; ms < 4; ms++)
      a[ms] = *(const half8*)(As + (wm * 64 + ms * 16 + l15) * LDA + ks + quad * 8);
#pragma unroll
    for (int ns = 0; ns < 4; ns++)
      b[ns] = *(const half8*)(Bs + (wn * 64 + ns * 16 + l15) * LDB + ks + quad * 8);
#pragma unroll
    for (int ms = 0; ms < 4; ms++)
#pragma unroll
      for (int ns = 0; ns < 4; ns++)
        acc[ms][ns] = __builtin_amdgcn_mfma_f32_16x16x32_f16(a[ms], b[ns], acc[ms][ns], 0, 0, 0);
  }
}

__device__ __forceinline__ void acc_zero(f32x4 acc[4][4]) {
#pragma unroll
  for (int ms = 0; ms < 4; ms++)
#pragma unroll
    for (int ns = 0; ns < 4; ns++)
#pragma unroll
      for (int u = 0; u < 4; u++) acc[ms][ns][u] = 0.f;
}

// C/D layout: b = wm*64+ms*16+quad*4+u, n = wn*64+ns*16+l15 (verified R2)
__device__ __forceinline__ void acc_store_split(const f32x4 acc[4][4], f16* H, f16* L,
                                                int rowoff, int wm, int wn, int l15, int quad) {
#pragma unroll
  for (int ms = 0; ms < 4; ms++)
#pragma unroll
    for (int ns = 0; ns < 4; ns++)
#pragma unroll
      for (int u = 0; u < 4; u++) {
        int row = rowoff + wm * 64 + ms * 16 + quad * 4 + u;
        int col = wn * 64 + ns * 16 + l15;
        float v = acc[ms][ns][u];
        f16 h = (f16)v;
        H[(size_t)row * NS + col] = h;
        L[(size_t)row * NS + col] = (f16)(v - (float)h);
      }
}

__device__ __forceinline__ void acc_load_f32(f32x4 acc[4][4], const float* src,
                                             int wm, int wn, int l15, int quad) {
#pragma unroll
  for (int ms = 0; ms < 4; ms++)
#pragma unroll
    for (int ns = 0; ns < 4; ns++)
#pragma unroll
      for (int u = 0; u < 4; u++)
        acc[ms][ns][u] = src[(size_t)(wm * 64 + ms * 16 + quad * 4 + u) * NS +
                             wn * 64 + ns * 16 + l15];
}

__device__ __forceinline__ void acc_store_f32(const f32x4 acc[4][4], float* dst,
                                              int wm, int wn, int l15, int quad) {
#pragma unroll
  for (int ms = 0; ms < 4; ms++)
#pragma unroll
    for (int ns = 0; ns < 4; ns++)
#pragma unroll
      for (int u = 0; u < 4; u++)
        dst[(size_t)(wm * 64 + ms * 16 + quad * 4 + u) * NS +
            wn * 64 + ns * 16 + l15] = acc[ms][ns][u];
}

// ===================== cooperative setup kernel (grid = 64 x 512) ==========
__global__ void __launch_bounds__(512)
k_setup(const float* __restrict__ x, const float* __restrict__ dA,
        const float* __restrict__ dB,
        f16* __restrict__ PrH, f16* __restrict__ PrL,
        f16* __restrict__ SQH, f16* __restrict__ SQL,
        f16* __restrict__ Kt, f16* __restrict__ xpad,
        float* __restrict__ V0, float* __restrict__ V1) {
  cg::grid_group grid = cg::this_grid();
  __shared__ alignas(16) f16 As[128 * LDA];
  __shared__ alignas(16) f16 Bs[256 * LDB];
  __shared__ float dBs[NS];
  int tid = threadIdx.x;
  int lane = tid & 63, wid = tid >> 6;
  int wm = wid >> 2, wn = wid & 3;
  int l15 = lane & 15, quad = lane >> 4;
  int bi = blockIdx.x;

  // --- phase 0: prep (xpad fp16 [s][b]; dA split hi/lo) ---
  {
    const int XPN = (PADROWS + SEQL) * NB;  // 270336
    for (int g = bi * 512 + tid; g < XPN; g += 64 * 512) {
      int s = g >> 7;  // /NB
      xpad[g] = (s < PADROWS) ? (f16)0.f : (f16)x[g - PADROWS * NB];
    }
    for (int g = bi * 512 + tid; g < NS * NS; g += 64 * 512) {
      float v = dA[g];
      f16 h = (f16)v;
      PrH[g] = h;
      PrL[g] = (f16)(v - (float)h);
    }
  }
  grid.sync();

  // --- phase 1: power doubling, dA^{m+r} = dA^m dA^r, r=1..m (split 3-pass) ---
#pragma unroll 1
  for (int m = 1; m <= 32; m <<= 1) {
    if (bi < 2 * m) {
      int prod = bi >> 1, mtile = bi & 1, r = prod + 1;
      const f16* AH = PrH + (size_t)(m - 1) * 65536;
      const f16* AL = PrL + (size_t)(m - 1) * 65536;
      const f16* BH = PrH + (size_t)(r - 1) * 65536;
      const f16* BL = PrL + (size_t)(r - 1) * 65536;
      f16* DH = PrH + (size_t)(m + r - 1) * 65536;
      f16* DL = PrL + (size_t)(m + r - 1) * 65536;
      f32x4 acc[4][4];
      acc_zero(acc);
#pragma unroll 1
      for (int pass = 0; pass < 3; pass++) {
        const f16* Asrc = (pass == 2) ? AL : AH;
        const f16* Bsrc = (pass == 1) ? BL : BH;
#pragma unroll 1
        for (int cc = 0; cc < 4; cc++) {
          stage_rows(As, LDA, 128, Asrc + (size_t)(mtile * 128) * NS + cc * 64, NS, 128, tid);
          stage_trans(Bs, Bsrc, cc * 64, tid);
          __syncthreads();
          mm64(As, Bs, acc, wm, wn, l15, quad);
          __syncthreads();
        }
      }
      acc_store_split(acc, DH, DL, mtile * 128, wm, wn, l15, quad);
    }
    grid.sync();
  }

  // --- phase 2: K[j] = dA^j dB, j=0..63 -> Kt[n][j] (stride 64), hi only ---
  {
    if (tid < NS) dBs[tid] = dB[tid];
    __syncthreads();
    int j = bi;
    if (tid < NS) {
      int n = tid;
      float a;
      if (j == 0) {
        a = dBs[n];
      } else {
        const f16* rh = PrH + (size_t)(j - 1) * 65536 + (size_t)n * NS;
        const f16* rl = PrL + (size_t)(j - 1) * 65536 + (size_t)n * NS;
        a = 0.f;
#pragma unroll 4
        for (int c = 0; c < NS; c += 8) {
          half8 vh = *(const half8*)(rh + c);
          half8 vl = *(const half8*)(rl + c);
#pragma unroll
          for (int u = 0; u < 8; u++) a += ((float)vh[u] + (float)vl[u]) * dBs[c + u];
        }
      }
      Kt[(size_t)n * 64 + j] = (f16)a;
    }
  }
  grid.sync();

  // --- phase 3: chunk sums U_k -> V0[k] fp32, k=0..30 ---
  if (bi < 31) {
    int k = bi, t = 64 * k + 63;
    f32x4 acc[4][4];
    acc_zero(acc);
    stage_revtrans(As, xpad, t, 64 * k, tid);
    stage_rows(Bs, LDB, 256, Kt, 64, 256, tid);
    __syncthreads();
    mm64(As, Bs, acc, wm, wn, l15, quad);
    __syncthreads();
    acc_store_f32(acc, V0 + (size_t)k * 32768, wm, wn, l15, quad);
  }
  grid.sync();

  // --- phase 4: Kogge-Stone scan, V_k += S^d V_{k-d}; fused S squarings ---
  const f16* PH = PrH + (size_t)63 * 65536;  // S = dA^64
  const f16* PL = PrL + (size_t)63 * 65536;
  const float* vin = V0;
  float* vout = V1;
  int rnd = 0;
#pragma unroll 1
  for (int d = 1; d <= 16; d <<= 1, rnd++) {
    if (bi < 31) {
      int k = bi;
      f32x4 acc[4][4];
      acc_load_f32(acc, vin + (size_t)k * 32768, wm, wn, l15, quad);
      if (k >= d) {
#pragma unroll 1
        for (int cc = 0; cc < 4; cc++) {
          stage_rows32(As, LDA, 128, vin + (size_t)(k - d) * 32768 + cc * 64, NS, tid);
          stage_rows(Bs, LDB, 256, PH + cc * 64, NS, 256, tid);
          __syncthreads();
          mm64(As, Bs, acc, wm, wn, l15, quad);
          __syncthreads();
          stage_rows(Bs, LDB, 256, PL + cc * 64, NS, 256, tid);
          __syncthreads();
          mm64(As, Bs, acc, wm, wn, l15, quad);
          __syncthreads();
        }
      }
      acc_store_f32(acc, vout + (size_t)k * 32768, wm, wn, l15, quad);
    } else if (bi < 33 && d < 16) {
      // squaring: S^{2d} = (S^d)^2, split 3-pass; tile mtile = bi-31
      int mtile = bi - 31;
      f16* DH = SQH + (size_t)rnd * 65536;
      f16* DL = SQL + (size_t)rnd * 65536;
      f32x4 acc[4][4];
      acc_zero(acc);
#pragma unroll 1
      for (int pass = 0; pass < 3; pass++) {
        const f16* Asrc = (pass == 2) ? PL : PH;
        const f16* Bsrc = (pass == 1) ? PL : PH;
#pragma unroll 1
        for (int cc = 0; cc < 4; cc++) {
          stage_rows(As, LDA, 128, Asrc + (size_t)(mtile * 128) * NS + cc * 64, NS, 128, tid);
          stage_trans(Bs, Bsrc, cc * 64, tid);
          __syncthreads();
          mm64(As, Bs, acc, wm, wn, l15, quad);
          __syncthreads();
        }
      }
      acc_store_split(acc, DH, DL, mtile * 128, wm, wn, l15, quad);
    }
    grid.sync();
    PH = SQH + (size_t)rnd * 65536;
    PL = SQL + (size_t)rnd * 65536;
    const float* t2 = vin;
    vin = vout;
    vout = (float*)t2;
  }
  // final scan result lives in V1 (5 rounds: V0->V1->V0->V1->V0->V1)
}

// --- pass2: Out[64k+r] = dA^{r+1} C_k + sum_{j<=r} K[j] x[t-j] ---
// C_k = Vfin[k-1] (fp32), C_0 = 0 (skip C-part for k=0).
__global__ void k_pass2(const f16* __restrict__ PrH, const f16* __restrict__ Kt,
                        const f16* __restrict__ xpad, const float* __restrict__ Vfin,
                        float* __restrict__ out) {
  __shared__ alignas(16) f16 As[128 * LDA];
  __shared__ alignas(16) f16 Bs[256 * LDB];
  int tid = threadIdx.x;
  int lane = tid & 63, wid = tid >> 6;
  int wm = wid >> 2, wn = wid & 3;
  int l15 = lane & 15, quad = lane >> 4;
  int bi = blockIdx.x;
  int r = bi >> 5, k = bi & 31;  // 32 consecutive blocks share dA^{r+1} (L2 locality)
  int t = 64 * k + r;
  const f16* G = PrH + (size_t)r * 65536;  // dA^{r+1}
  f32x4 acc[4][4];
  acc_zero(acc);
  if (k > 0) {
    const float* C = Vfin + (size_t)(k - 1) * 32768;
#pragma unroll 1
    for (int cc = 0; cc < 4; cc++) {  // C-part, inner dim m = 256
      stage_rows32(As, LDA, 128, C + cc * 64, NS, tid);
      stage_rows(Bs, LDB, 256, G + cc * 64, NS, 256, tid);
      __syncthreads();
      mm64(As, Bs, acc, wm, wn, l15, quad);
      __syncthreads();
    }
  }
  // window part, inner dim j = 64; mask j > r  <=>  s = t - j < 64k
  stage_revtrans(As, xpad, t, 64 * k, tid);
  stage_rows(Bs, LDB, 256, Kt, 64, 256, tid);
  __syncthreads();
  mm64(As, Bs, acc, wm, wn, l15, quad);
  __syncthreads();
  acc_store_f32(acc, out + (size_t)t * (NB * NS), wm, wn, l15, quad);
}

extern "C" void kernel_launch(void* const* d_in, const int* in_sizes, int n_in,
                              void* d_out, int out_size, void* d_ws, size_t ws_size,
                              hipStream_t stream) {
  const float* x = (const float*)d_in[0];   // (2048, 128)
  const float* dA = (const float*)d_in[1];  // (256, 256)
  const float* dB = (const float*)d_in[2];  // (256,)
  float* out = (float*)d_out;

  char* ws = (char*)d_ws;
  f16* PrH = (f16*)(ws + 0);          // 64 x 65536 f16 (dA^1..dA^64) hi
  f16* PrL = (f16*)(ws + 8388608);    // lo
  f16* SQH = (f16*)(ws + 16777216);   // 4 x 65536 f16 (dA^{128,256,512,1024}) hi
  f16* SQL = (f16*)(ws + 17301504);   // lo
  f16* Kt  = (f16*)(ws + 17825792);   // [n][j] 256x64 f16
  f16* Xp  = (f16*)(ws + 17858560);   // [2112][128] f16
  float* V0 = (float*)(ws + 18399232);  // 31 x 128x256 fp32 scan ping
  float* V1 = (float*)(ws + 22462464);  // pong (final C states)
  // total ws use: 26,525,696 B (~25.3 MB)

  void* args[] = {&x, &dA, &dB, &PrH, &PrL, &SQH, &SQL, &Kt, &Xp, &V0, &V1};
  hipLaunchCooperativeKernel(reinterpret_cast<void*>(k_setup), dim3(64), dim3(512),
                             args, 0, stream);
  k_pass2<<<2048, 512, 0, stream>>>(PrH, Kt, Xp, V1, out);
}